// Round 1
// baseline (820.789 us; speedup 1.0000x reference)
//
#include <hip/hip_runtime.h>
#include <hip/hip_bf16.h>
#include <stdint.h>

#define N_NODES 50000
#define N_EDGES 800000
#define H_DIM 128
#define N_REL 40
#define N_BASES 4

typedef __attribute__((ext_vector_type(8))) short bf16x8;
typedef __attribute__((ext_vector_type(4))) float f32x4;

// round-to-nearest-even f32 -> bf16 bits
__device__ __forceinline__ unsigned short f2bf(float f) {
    unsigned int u = __float_as_uint(f);
    unsigned int r = u + 0x7fffu + ((u >> 16) & 1u);
    return (unsigned short)(r >> 16);
}

// K0: WT[mat][j][k] = W[mat][k][j] cast to bf16. mats 0..3 = basis_w, 4 = loop_w.
__global__ __launch_bounds__(256) void transpose_w(
        const float* __restrict__ basis_w,
        const float* __restrict__ loop_w,
        unsigned short* __restrict__ wt) {
    int mat = blockIdx.x;
    const float* src = (mat < 4) ? (basis_w + mat * 16384) : loop_w;
    unsigned short* dst = wt + mat * 16384;
    int t = threadIdx.x;
#pragma unroll
    for (int i = 0; i < 16; ++i) {
        int f = t + i * 256;            // [0, 4096) float4 index
        int k = f >> 5;                 // row of source (k)
        int j4 = (f & 31) * 4;          // col of source (j)
        float4 v = ((const float4*)src)[f];
        dst[(j4 + 0) * 128 + k] = f2bf(v.x);
        dst[(j4 + 1) * 128 + k] = f2bf(v.y);
        dst[(j4 + 2) * 128 + k] = f2bf(v.z);
        dst[(j4 + 3) * 128 + k] = f2bf(v.w);
    }
}

// K1: for mat<4:  hb[n][mat*128+col] = (bf16)(h[n,:] @ basis_w[mat])[col]
//     for mat==4: out[n][col] = bias[col] + (h[n,:] @ loop_w)[col]   (f32 accumulator)
// LDS-free MFMA GEMM: each wave computes a 32x128 strip. grid = (391, 5), block = 256.
__global__ __launch_bounds__(256) void gemm_transform(
        const float* __restrict__ h,
        const unsigned short* __restrict__ wt,
        const float* __restrict__ bias,
        unsigned short* __restrict__ hb,
        float* __restrict__ out) {
    int mat  = blockIdx.y;
    int wv   = threadIdx.x >> 6;
    int lane = threadIdx.x & 63;
    int n16  = lane & 15;
    int quad = lane >> 4;
    int r0w  = (blockIdx.x * 4 + wv) * 32;

    const unsigned short* wtm = wt + mat * 16384;

    f32x4 acc[2][8];
#pragma unroll
    for (int rt = 0; rt < 2; ++rt)
#pragma unroll
        for (int ct = 0; ct < 8; ++ct)
            acc[rt][ct] = (f32x4)0.f;

#pragma unroll
    for (int ks = 0; ks < 4; ++ks) {
        int k0 = ks * 32 + quad * 8;
        bf16x8 afrag[2];
#pragma unroll
        for (int rt = 0; rt < 2; ++rt) {
            int r = r0w + rt * 16 + n16;
            bf16x8 af = (bf16x8)0;
            if (r < N_NODES) {
                const float* ap = h + (size_t)r * H_DIM + k0;
                float4 a0 = ((const float4*)ap)[0];
                float4 a1 = ((const float4*)ap)[1];
                af[0] = (short)f2bf(a0.x); af[1] = (short)f2bf(a0.y);
                af[2] = (short)f2bf(a0.z); af[3] = (short)f2bf(a0.w);
                af[4] = (short)f2bf(a1.x); af[5] = (short)f2bf(a1.y);
                af[6] = (short)f2bf(a1.z); af[7] = (short)f2bf(a1.w);
            }
            afrag[rt] = af;
        }
#pragma unroll
        for (int ct = 0; ct < 8; ++ct) {
            const unsigned short* bp = wtm + (ct * 16 + n16) * 128 + k0;
            bf16x8 bfrag = *(const bf16x8*)bp;   // 16B aligned
            acc[0][ct] = __builtin_amdgcn_mfma_f32_16x16x32_bf16(afrag[0], bfrag, acc[0][ct], 0, 0, 0);
            acc[1][ct] = __builtin_amdgcn_mfma_f32_16x16x32_bf16(afrag[1], bfrag, acc[1][ct], 0, 0, 0);
        }
    }

    // C/D layout: col = lane&15 (within 16-tile), row = quad*4 + reg
    if (mat < 4) {
#pragma unroll
        for (int rt = 0; rt < 2; ++rt) {
            int rbase = r0w + rt * 16 + quad * 4;
#pragma unroll
            for (int ct = 0; ct < 8; ++ct) {
                int col = ct * 16 + n16;
#pragma unroll
                for (int rg = 0; rg < 4; ++rg) {
                    int r = rbase + rg;
                    if (r < N_NODES)
                        hb[(size_t)r * 512 + mat * 128 + col] = f2bf(acc[rt][ct][rg]);
                }
            }
        }
    } else {
#pragma unroll
        for (int rt = 0; rt < 2; ++rt) {
            int rbase = r0w + rt * 16 + quad * 4;
#pragma unroll
            for (int ct = 0; ct < 8; ++ct) {
                int col = ct * 16 + n16;
                float bv = bias[col];
#pragma unroll
                for (int rg = 0; rg < 4; ++rg) {
                    int r = rbase + rg;
                    if (r < N_NODES)
                        out[(size_t)r * H_DIM + col] = acc[rt][ct][rg] + bv;
                }
            }
        }
    }
}

// K2: one wave per edge; lane handles channels (2*lane, 2*lane+1).
// m_e = sum_b coeff_b * hb[src][b][:], atomicAdd into out[dst].
__global__ __launch_bounds__(256) void edge_scatter(
        const int* __restrict__ src, const int* __restrict__ dst,
        const int* __restrict__ etype, const float* __restrict__ norm,
        const float* __restrict__ w_comp,
        const unsigned short* __restrict__ hb,
        float* __restrict__ out) {
    int e = blockIdx.x * 4 + (threadIdx.x >> 6);
    if (e >= N_EDGES) return;
    int lane = threadIdx.x & 63;

    int s = src[e];
    int d = dst[e];
    int r = etype[e];
    float nm = norm[e];
    float4 wc = ((const float4*)w_comp)[r];   // w_comp row, 16B aligned
    float c0 = wc.x * nm, c1 = wc.y * nm, c2 = wc.z * nm, c3 = wc.w * nm;

    const unsigned int* hp = (const unsigned int*)(hb + (size_t)s * 512);
    unsigned int u0 = hp[lane];
    unsigned int u1 = hp[64 + lane];
    unsigned int u2 = hp[128 + lane];
    unsigned int u3 = hp[192 + lane];

    float lo0 = __uint_as_float(u0 << 16), hi0 = __uint_as_float(u0 & 0xffff0000u);
    float lo1 = __uint_as_float(u1 << 16), hi1 = __uint_as_float(u1 & 0xffff0000u);
    float lo2 = __uint_as_float(u2 << 16), hi2 = __uint_as_float(u2 & 0xffff0000u);
    float lo3 = __uint_as_float(u3 << 16), hi3 = __uint_as_float(u3 & 0xffff0000u);

    float m0 = c0 * lo0 + c1 * lo1 + c2 * lo2 + c3 * lo3;
    float m1 = c0 * hi0 + c1 * hi1 + c2 * hi2 + c3 * hi3;

    float* op = out + (size_t)d * H_DIM + lane * 2;
    unsafeAtomicAdd(op, m0);
    unsafeAtomicAdd(op + 1, m1);
}

// K3: in-place ReLU over out (6.4M f32 = 1.6M float4)
__global__ __launch_bounds__(256) void relu_kernel(float* __restrict__ out) {
    int i = blockIdx.x * blockDim.x + threadIdx.x;
    if (i < 1600000) {
        float4* p = (float4*)out;
        float4 v = p[i];
        v.x = fmaxf(v.x, 0.f);
        v.y = fmaxf(v.y, 0.f);
        v.z = fmaxf(v.z, 0.f);
        v.w = fmaxf(v.w, 0.f);
        p[i] = v;
    }
}

extern "C" void kernel_launch(void* const* d_in, const int* in_sizes, int n_in,
                              void* d_out, int out_size, void* d_ws, size_t ws_size,
                              hipStream_t stream) {
    const float* h       = (const float*)d_in[0];
    const float* norm    = (const float*)d_in[1];
    const float* basis_w = (const float*)d_in[2];
    const float* w_comp  = (const float*)d_in[3];
    const float* loop_w  = (const float*)d_in[4];
    const float* bias    = (const float*)d_in[5];
    const int*   src     = (const int*)d_in[6];
    const int*   dst     = (const int*)d_in[7];
    const int*   etype   = (const int*)d_in[8];
    float* out = (float*)d_out;

    // ws layout: WT bf16 [5][128][128] = 163840 B, then hb bf16 [50000][512] = 51.2 MB
    unsigned short* wt = (unsigned short*)d_ws;
    unsigned short* hb = (unsigned short*)((char*)d_ws + 163840);

    transpose_w<<<5, 256, 0, stream>>>(basis_w, loop_w, wt);
    gemm_transform<<<dim3(391, 5), 256, 0, stream>>>(h, wt, bias, hb, out);
    edge_scatter<<<200000, 256, 0, stream>>>(src, dst, etype, norm, w_comp, hb, out);
    relu_kernel<<<6250, 256, 0, stream>>>(out);
}

// Round 2
// 341.644 us; speedup vs baseline: 2.4025x; 2.4025x over previous
//
#include <hip/hip_runtime.h>
#include <hip/hip_bf16.h>
#include <stdint.h>

#define N_NODES 50000
#define N_EDGES 800000
#define H_DIM 128
#define N_REL 40
#define N_BASES 4

typedef __attribute__((ext_vector_type(8))) short bf16x8;
typedef __attribute__((ext_vector_type(4))) float f32x4;

// round-to-nearest-even f32 -> bf16 bits
__device__ __forceinline__ unsigned short f2bf(float f) {
    unsigned int u = __float_as_uint(f);
    unsigned int r = u + 0x7fffu + ((u >> 16) & 1u);
    return (unsigned short)(r >> 16);
}

// ---------------------------------------------------------------------------
// K0: build wt2[j][kg] = Wstack[kg][j] in bf16, where Wstack (640 x 128) is
// [loop_w (k 0..127); basis_w[b] (k 128+128b .. )]. One block per source mat.
__global__ __launch_bounds__(256) void transpose_w2(
        const float* __restrict__ basis_w,
        const float* __restrict__ loop_w,
        unsigned short* __restrict__ wt2) {
    int mat = blockIdx.x;                       // 0..3 basis, 4 loop
    const float* src = (mat < 4) ? (basis_w + mat * 16384) : loop_w;
    int koff = (mat < 4) ? (128 + mat * 128) : 0;
    int t = threadIdx.x;
#pragma unroll
    for (int i = 0; i < 16; ++i) {
        int f = t + i * 256;                    // [0,4096) float4 index
        int k = f >> 5;                         // source row (k)
        int j4 = (f & 31) * 4;                  // source col (j)
        float4 v = ((const float4*)src)[f];
        wt2[(size_t)(j4 + 0) * 640 + koff + k] = f2bf(v.x);
        wt2[(size_t)(j4 + 1) * 640 + koff + k] = f2bf(v.y);
        wt2[(size_t)(j4 + 2) * 640 + koff + k] = f2bf(v.z);
        wt2[(size_t)(j4 + 3) * 640 + koff + k] = f2bf(v.w);
    }
}

// K1: hbf[n][c] = (bf16) h[n][c]  (12.8 MB compact buffer for edge gathers)
__global__ __launch_bounds__(256) void cast_h(
        const float* __restrict__ h, unsigned short* __restrict__ hbf) {
    int t = blockIdx.x * 256 + threadIdx.x;     // 800000 threads, 8 elems each
    int row = t >> 4;
    int cb = (t & 15) * 8;
    const float* p = h + (size_t)row * 128 + cb;
    float4 a0 = ((const float4*)p)[0];
    float4 a1 = ((const float4*)p)[1];
    bf16x8 o;
    o[0] = (short)f2bf(a0.x); o[1] = (short)f2bf(a0.y);
    o[2] = (short)f2bf(a0.z); o[3] = (short)f2bf(a0.w);
    o[4] = (short)f2bf(a1.x); o[5] = (short)f2bf(a1.y);
    o[6] = (short)f2bf(a1.z); o[7] = (short)f2bf(a1.w);
    *(bf16x8*)(hbf + (size_t)row * 128 + cb) = o;
}

// K2: zero the degree histogram
__global__ __launch_bounds__(256) void zero_cnt(int* __restrict__ cnt) {
    int i = blockIdx.x * 256 + threadIdx.x;
    if (i < N_NODES) cnt[i] = 0;
}

// K3: degree histogram over dst
__global__ __launch_bounds__(256) void hist_kernel(
        const int* __restrict__ dst, int* __restrict__ cnt) {
    int e = blockIdx.x * 256 + threadIdx.x;
    if (e < N_EDGES) atomicAdd(&cnt[dst[e]], 1);
}

// K4: exclusive scan of cnt -> offs[0..N], plus a working copy in cursor.
// Single block of 1024 threads (16 waves), wave-shuffle scan.
__global__ __launch_bounds__(1024) void scan_kernel(
        const int* __restrict__ cnt, int* __restrict__ offs,
        int* __restrict__ cursor) {
    __shared__ int wsum[16];
    int t = threadIdx.x;
    int lane = t & 63;
    int w = t >> 6;
    int carry = 0;
    for (int base = 0; base < N_NODES; base += 1024) {
        int i = base + t;
        int x = (i < N_NODES) ? cnt[i] : 0;
        int v = x;
#pragma unroll
        for (int d = 1; d < 64; d <<= 1) {
            int y = __shfl_up(v, d);
            if (lane >= d) v += y;
        }
        if (lane == 63) wsum[w] = v;
        __syncthreads();
        if (w == 0) {
            int ws_ = (lane < 16) ? wsum[lane] : 0;
#pragma unroll
            for (int d = 1; d < 16; d <<= 1) {
                int y = __shfl_up(ws_, d);
                if (lane >= d) ws_ += y;
            }
            if (lane < 16) wsum[lane] = ws_;
        }
        __syncthreads();
        int wprefix = (w == 0) ? 0 : wsum[w - 1];
        int excl = carry + wprefix + v - x;
        if (i < N_NODES) { offs[i] = excl; cursor[i] = excl; }
        carry += wsum[15];
        __syncthreads();
    }
    if (t == 0) offs[N_NODES] = carry;
}

// K5: scatter edges into dst-sorted order; precompute per-edge coeffs.
__global__ __launch_bounds__(256) void scatter_kernel(
        const int* __restrict__ src, const int* __restrict__ dst,
        const int* __restrict__ etype, const float* __restrict__ norm,
        const float* __restrict__ w_comp, int* __restrict__ cursor,
        int* __restrict__ sorted_src, float4* __restrict__ sorted_cf) {
    int e = blockIdx.x * 256 + threadIdx.x;
    if (e >= N_EDGES) return;
    int d = dst[e];
    int pos = atomicAdd(&cursor[d], 1);
    sorted_src[pos] = src[e];
    float nm = norm[e];
    float4 wc = ((const float4*)w_comp)[etype[e]];
    float4 cf;
    cf.x = wc.x * nm; cf.y = wc.y * nm; cf.z = wc.z * nm; cf.w = wc.w * nm;
    sorted_cf[pos] = cf;
}

// K6: per-node aggregation (no atomics). One wave per node; lane handles
// channels (2*lane, 2*lane+1). S[v][b*128 + c] = sum_{e->v} cf[b]*hbf[src_e][c]
__global__ __launch_bounds__(256) void aggregate_kernel(
        const int* __restrict__ offs, const int* __restrict__ sorted_src,
        const float4* __restrict__ sorted_cf,
        const unsigned short* __restrict__ hbf,
        unsigned short* __restrict__ S) {
    int v = blockIdx.x * 4 + (threadIdx.x >> 6);
    if (v >= N_NODES) return;
    int lane = threadIdx.x & 63;
    int begin = offs[v];
    int end = offs[v + 1];

    float a0l = 0.f, a0h = 0.f, a1l = 0.f, a1h = 0.f;
    float a2l = 0.f, a2h = 0.f, a3l = 0.f, a3h = 0.f;

    const unsigned int* hrows = (const unsigned int*)hbf;

    for (int b0 = begin; b0 < end; b0 += 64) {
        int m = end - b0;
        int sl = 0;
        float4 cfl = make_float4(0.f, 0.f, 0.f, 0.f);
        if (lane < m) {
            sl = sorted_src[b0 + lane];
            cfl = sorted_cf[b0 + lane];
        }
        int mm = m < 64 ? m : 64;
        for (int j = 0; j < mm; ++j) {
            int s = __shfl(sl, j);
            float c0 = __shfl(cfl.x, j);
            float c1 = __shfl(cfl.y, j);
            float c2 = __shfl(cfl.z, j);
            float c3 = __shfl(cfl.w, j);
            unsigned int u = hrows[(size_t)s * 64 + lane];
            float lo = __uint_as_float(u << 16);
            float hi = __uint_as_float(u & 0xffff0000u);
            a0l += c0 * lo; a0h += c0 * hi;
            a1l += c1 * lo; a1h += c1 * hi;
            a2l += c2 * lo; a2h += c2 * hi;
            a3l += c3 * lo; a3h += c3 * hi;
        }
    }

    unsigned int* ps = (unsigned int*)(S + (size_t)v * 512);
    ps[0 * 64 + lane] = (unsigned int)f2bf(a0l) | ((unsigned int)f2bf(a0h) << 16);
    ps[1 * 64 + lane] = (unsigned int)f2bf(a1l) | ((unsigned int)f2bf(a1h) << 16);
    ps[2 * 64 + lane] = (unsigned int)f2bf(a2l) | ((unsigned int)f2bf(a2h) << 16);
    ps[3 * 64 + lane] = (unsigned int)f2bf(a3l) | ((unsigned int)f2bf(a3h) << 16);
}

// K7: out = relu(bias + [hbf | S] @ Wstack)   (K=640 MFMA GEMM, relu fused)
__global__ __launch_bounds__(256) void gemm_out(
        const unsigned short* __restrict__ hbf,
        const unsigned short* __restrict__ S,
        const unsigned short* __restrict__ wt2,
        const float* __restrict__ bias,
        float* __restrict__ out) {
    int wv = threadIdx.x >> 6;
    int lane = threadIdx.x & 63;
    int n16 = lane & 15;
    int quad = lane >> 4;
    int r0w = (blockIdx.x * 4 + wv) * 32;

    f32x4 acc[2][8];
#pragma unroll
    for (int rt = 0; rt < 2; ++rt)
#pragma unroll
        for (int ct = 0; ct < 8; ++ct)
            acc[rt][ct] = (f32x4)0.f;

#pragma unroll
    for (int ks = 0; ks < 20; ++ks) {
        int k0 = ks * 32 + quad * 8;
        bf16x8 afrag[2];
#pragma unroll
        for (int rt = 0; rt < 2; ++rt) {
            int r = r0w + rt * 16 + n16;
            bf16x8 af = (bf16x8)0;
            if (r < N_NODES) {
                const unsigned short* ap = (k0 < 128)
                    ? (hbf + (size_t)r * 128 + k0)
                    : (S + (size_t)r * 512 + (k0 - 128));
                af = *(const bf16x8*)ap;
            }
            afrag[rt] = af;
        }
#pragma unroll
        for (int ct = 0; ct < 8; ++ct) {
            const unsigned short* bp = wt2 + (size_t)(ct * 16 + n16) * 640 + k0;
            bf16x8 bfrag = *(const bf16x8*)bp;
            acc[0][ct] = __builtin_amdgcn_mfma_f32_16x16x32_bf16(afrag[0], bfrag, acc[0][ct], 0, 0, 0);
            acc[1][ct] = __builtin_amdgcn_mfma_f32_16x16x32_bf16(afrag[1], bfrag, acc[1][ct], 0, 0, 0);
        }
    }

    // C/D layout: col = lane&15, row = quad*4 + reg
#pragma unroll
    for (int rt = 0; rt < 2; ++rt) {
        int rbase = r0w + rt * 16 + quad * 4;
#pragma unroll
        for (int ct = 0; ct < 8; ++ct) {
            int col = ct * 16 + n16;
            float bv = bias[col];
#pragma unroll
            for (int rg = 0; rg < 4; ++rg) {
                int r = rbase + rg;
                if (r < N_NODES)
                    out[(size_t)r * H_DIM + col] = fmaxf(acc[rt][ct][rg] + bv, 0.f);
            }
        }
    }
}

extern "C" void kernel_launch(void* const* d_in, const int* in_sizes, int n_in,
                              void* d_out, int out_size, void* d_ws, size_t ws_size,
                              hipStream_t stream) {
    const float* h       = (const float*)d_in[0];
    const float* norm    = (const float*)d_in[1];
    const float* basis_w = (const float*)d_in[2];
    const float* w_comp  = (const float*)d_in[3];
    const float* loop_w  = (const float*)d_in[4];
    const float* bias    = (const float*)d_in[5];
    const int*   src     = (const int*)d_in[6];
    const int*   dst     = (const int*)d_in[7];
    const int*   etype   = (const int*)d_in[8];
    float* out = (float*)d_out;

    // ws layout (bytes):
    char* base = (char*)d_ws;
    unsigned short* wt2        = (unsigned short*)(base + 0);          // 163,840
    unsigned short* hbf        = (unsigned short*)(base + 163840);     // 12,800,000
    unsigned short* S          = (unsigned short*)(base + 12963840);   // 51,200,000
    int*            cnt        = (int*)(base + 64163840);              // 200,000
    int*            offs       = (int*)(base + 64363840);              // 200,064
    int*            cursor     = (int*)(base + 64563904);              // 200,000
    int*            sorted_src = (int*)(base + 64763904);              // 3,200,000
    float4*         sorted_cf  = (float4*)(base + 67963904);           // 12,800,000
    // total ~80.8 MB

    transpose_w2<<<5, 256, 0, stream>>>(basis_w, loop_w, wt2);
    cast_h<<<3125, 256, 0, stream>>>(h, hbf);
    zero_cnt<<<196, 256, 0, stream>>>(cnt);
    hist_kernel<<<3125, 256, 0, stream>>>(dst, cnt);
    scan_kernel<<<1, 1024, 0, stream>>>(cnt, offs, cursor);
    scatter_kernel<<<3125, 256, 0, stream>>>(src, dst, etype, norm, w_comp,
                                             cursor, sorted_src, sorted_cf);
    aggregate_kernel<<<12500, 256, 0, stream>>>(offs, sorted_src, sorted_cf, hbf, S);
    gemm_out<<<391, 256, 0, stream>>>(hbf, S, wt2, bias, out);
}

// Round 3
// 280.675 us; speedup vs baseline: 2.9243x; 1.2172x over previous
//
#include <hip/hip_runtime.h>
#include <hip/hip_bf16.h>
#include <stdint.h>

#define N_NODES 50000
#define N_EDGES 800000
#define H_DIM 128
#define N_REL 40
#define N_BASES 4

typedef __attribute__((ext_vector_type(8))) short bf16x8;
typedef __attribute__((ext_vector_type(4))) float f32x4;

// round-to-nearest-even f32 -> bf16 bits
__device__ __forceinline__ unsigned short f2bf(float f) {
    unsigned int u = __float_as_uint(f);
    unsigned int r = u + 0x7fffu + ((u >> 16) & 1u);
    return (unsigned short)(r >> 16);
}

// ---------------------------------------------------------------------------
// K0: build wt2[j][kg] = Wstack[kg][j] in bf16, where Wstack (640 x 128) is
// [loop_w (k 0..127); basis_w[b] (k 128+128b .. )]. One block per source mat.
__global__ __launch_bounds__(256) void transpose_w2(
        const float* __restrict__ basis_w,
        const float* __restrict__ loop_w,
        unsigned short* __restrict__ wt2) {
    int mat = blockIdx.x;                       // 0..3 basis, 4 loop
    const float* src = (mat < 4) ? (basis_w + mat * 16384) : loop_w;
    int koff = (mat < 4) ? (128 + mat * 128) : 0;
    int t = threadIdx.x;
#pragma unroll
    for (int i = 0; i < 16; ++i) {
        int f = t + i * 256;                    // [0,4096) float4 index
        int k = f >> 5;                         // source row (k)
        int j4 = (f & 31) * 4;                  // source col (j)
        float4 v = ((const float4*)src)[f];
        wt2[(size_t)(j4 + 0) * 640 + koff + k] = f2bf(v.x);
        wt2[(size_t)(j4 + 1) * 640 + koff + k] = f2bf(v.y);
        wt2[(size_t)(j4 + 2) * 640 + koff + k] = f2bf(v.z);
        wt2[(size_t)(j4 + 3) * 640 + koff + k] = f2bf(v.w);
    }
}

// K1: hbf[n][c] = (bf16) h[n][c]  (12.8 MB compact buffer for edge gathers)
__global__ __launch_bounds__(256) void cast_h(
        const float* __restrict__ h, unsigned short* __restrict__ hbf) {
    int t = blockIdx.x * 256 + threadIdx.x;     // 800000 threads, 8 elems each
    int row = t >> 4;
    int cb = (t & 15) * 8;
    const float* p = h + (size_t)row * 128 + cb;
    float4 a0 = ((const float4*)p)[0];
    float4 a1 = ((const float4*)p)[1];
    bf16x8 o;
    o[0] = (short)f2bf(a0.x); o[1] = (short)f2bf(a0.y);
    o[2] = (short)f2bf(a0.z); o[3] = (short)f2bf(a0.w);
    o[4] = (short)f2bf(a1.x); o[5] = (short)f2bf(a1.y);
    o[6] = (short)f2bf(a1.z); o[7] = (short)f2bf(a1.w);
    *(bf16x8*)(hbf + (size_t)row * 128 + cb) = o;
}

// K2: zero the degree histogram
__global__ __launch_bounds__(256) void zero_cnt(int* __restrict__ cnt) {
    int i = blockIdx.x * 256 + threadIdx.x;
    if (i < N_NODES) cnt[i] = 0;
}

// K3: degree histogram over dst
__global__ __launch_bounds__(256) void hist_kernel(
        const int* __restrict__ dst, int* __restrict__ cnt) {
    int e = blockIdx.x * 256 + threadIdx.x;
    if (e < N_EDGES) atomicAdd(&cnt[dst[e]], 1);
}

// K4a: per-block (256-elem) exclusive scan; writes local scan + block sums.
__global__ __launch_bounds__(256) void scan_local(
        const int* __restrict__ cnt, int* __restrict__ offs,
        int* __restrict__ bsum) {
    __shared__ int wsum[4];
    int t = threadIdx.x, lane = t & 63, w = t >> 6;
    int i = blockIdx.x * 256 + t;
    int x = (i < N_NODES) ? cnt[i] : 0;
    int v = x;
#pragma unroll
    for (int d = 1; d < 64; d <<= 1) {
        int y = __shfl_up(v, d);
        if (lane >= d) v += y;
    }
    if (lane == 63) wsum[w] = v;
    __syncthreads();
    int wpre = 0;
    if (w > 0) wpre += wsum[0];
    if (w > 1) wpre += wsum[1];
    if (w > 2) wpre += wsum[2];
    if (i < N_NODES) offs[i] = wpre + v - x;
    if (t == 255) bsum[blockIdx.x] = wpre + v;
}

// K4b: scan the 196 block sums (single 256-thread block); writes grand total.
__global__ __launch_bounds__(256) void scan_bsum(
        const int* __restrict__ bsum, int* __restrict__ bpre,
        int* __restrict__ offs) {
    __shared__ int wsum[4];
    int t = threadIdx.x, lane = t & 63, w = t >> 6;
    int x = (t < 196) ? bsum[t] : 0;
    int v = x;
#pragma unroll
    for (int d = 1; d < 64; d <<= 1) {
        int y = __shfl_up(v, d);
        if (lane >= d) v += y;
    }
    if (lane == 63) wsum[w] = v;
    __syncthreads();
    int wpre = 0;
    if (w > 0) wpre += wsum[0];
    if (w > 1) wpre += wsum[1];
    if (w > 2) wpre += wsum[2];
    if (t < 196) bpre[t] = wpre + v - x;
    if (t == 255) offs[N_NODES] = wpre + v;   // = N_EDGES
}

// K4c: add block prefixes; also initialize cursor.
__global__ __launch_bounds__(256) void scan_add(
        int* __restrict__ offs, const int* __restrict__ bpre,
        int* __restrict__ cursor) {
    int i = blockIdx.x * 256 + threadIdx.x;
    if (i < N_NODES) {
        int o = offs[i] + bpre[blockIdx.x];
        offs[i] = o;
        cursor[i] = o;
    }
}

// K5: scatter edges into dst-sorted order; precompute per-edge coeffs.
__global__ __launch_bounds__(256) void scatter_kernel(
        const int* __restrict__ src, const int* __restrict__ dst,
        const int* __restrict__ etype, const float* __restrict__ norm,
        const float* __restrict__ w_comp, int* __restrict__ cursor,
        int* __restrict__ sorted_src, float4* __restrict__ sorted_cf) {
    int e = blockIdx.x * 256 + threadIdx.x;
    if (e >= N_EDGES) return;
    int d = dst[e];
    int pos = atomicAdd(&cursor[d], 1);
    sorted_src[pos] = src[e];
    float nm = norm[e];
    float4 wc = ((const float4*)w_comp)[etype[e]];
    float4 cf;
    cf.x = wc.x * nm; cf.y = wc.y * nm; cf.z = wc.z * nm; cf.w = wc.w * nm;
    sorted_cf[pos] = cf;
}

// K6: per-node aggregation, no atomics, no shuffles. One wave per node;
// edge metadata is wave-uniform -> scalar loads; gather uses saddr form.
// S[v][b*128 + c] = sum_{e->v} cf[b] * hbf[src_e][c]
__global__ __launch_bounds__(256) void aggregate_kernel(
        const int* __restrict__ offs, const int* __restrict__ sorted_src,
        const float4* __restrict__ sorted_cf,
        const unsigned short* __restrict__ hbf,
        unsigned short* __restrict__ S) {
    int v = __builtin_amdgcn_readfirstlane(blockIdx.x * 4 + (threadIdx.x >> 6));
    if (v >= N_NODES) return;
    int lane = threadIdx.x & 63;
    int begin = offs[v];
    int end = offs[v + 1];

    float a0l = 0.f, a0h = 0.f, a1l = 0.f, a1h = 0.f;
    float a2l = 0.f, a2h = 0.f, a3l = 0.f, a3h = 0.f;

    const unsigned int* hrows = (const unsigned int*)hbf;

    int j = begin;
    for (; j + 4 <= end; j += 4) {
        int s0 = sorted_src[j + 0];
        int s1 = sorted_src[j + 1];
        int s2 = sorted_src[j + 2];
        int s3 = sorted_src[j + 3];
        float4 c0 = sorted_cf[j + 0];
        float4 c1 = sorted_cf[j + 1];
        float4 c2 = sorted_cf[j + 2];
        float4 c3 = sorted_cf[j + 3];
        unsigned int u0 = hrows[(size_t)s0 * 64 + lane];
        unsigned int u1 = hrows[(size_t)s1 * 64 + lane];
        unsigned int u2 = hrows[(size_t)s2 * 64 + lane];
        unsigned int u3 = hrows[(size_t)s3 * 64 + lane];

        float lo, hi;
        lo = __uint_as_float(u0 << 16); hi = __uint_as_float(u0 & 0xffff0000u);
        a0l += c0.x * lo; a0h += c0.x * hi;
        a1l += c0.y * lo; a1h += c0.y * hi;
        a2l += c0.z * lo; a2h += c0.z * hi;
        a3l += c0.w * lo; a3h += c0.w * hi;
        lo = __uint_as_float(u1 << 16); hi = __uint_as_float(u1 & 0xffff0000u);
        a0l += c1.x * lo; a0h += c1.x * hi;
        a1l += c1.y * lo; a1h += c1.y * hi;
        a2l += c1.z * lo; a2h += c1.z * hi;
        a3l += c1.w * lo; a3h += c1.w * hi;
        lo = __uint_as_float(u2 << 16); hi = __uint_as_float(u2 & 0xffff0000u);
        a0l += c2.x * lo; a0h += c2.x * hi;
        a1l += c2.y * lo; a1h += c2.y * hi;
        a2l += c2.z * lo; a2h += c2.z * hi;
        a3l += c2.w * lo; a3h += c2.w * hi;
        lo = __uint_as_float(u3 << 16); hi = __uint_as_float(u3 & 0xffff0000u);
        a0l += c3.x * lo; a0h += c3.x * hi;
        a1l += c3.y * lo; a1h += c3.y * hi;
        a2l += c3.z * lo; a2h += c3.z * hi;
        a3l += c3.w * lo; a3h += c3.w * hi;
    }
    for (; j < end; ++j) {
        int s = sorted_src[j];
        float4 cf = sorted_cf[j];
        unsigned int u = hrows[(size_t)s * 64 + lane];
        float lo = __uint_as_float(u << 16);
        float hi = __uint_as_float(u & 0xffff0000u);
        a0l += cf.x * lo; a0h += cf.x * hi;
        a1l += cf.y * lo; a1h += cf.y * hi;
        a2l += cf.z * lo; a2h += cf.z * hi;
        a3l += cf.w * lo; a3h += cf.w * hi;
    }

    unsigned int* ps = (unsigned int*)(S + (size_t)v * 512);
    ps[0 * 64 + lane] = (unsigned int)f2bf(a0l) | ((unsigned int)f2bf(a0h) << 16);
    ps[1 * 64 + lane] = (unsigned int)f2bf(a1l) | ((unsigned int)f2bf(a1h) << 16);
    ps[2 * 64 + lane] = (unsigned int)f2bf(a2l) | ((unsigned int)f2bf(a2h) << 16);
    ps[3 * 64 + lane] = (unsigned int)f2bf(a3l) | ((unsigned int)f2bf(a3h) << 16);
}

// K7: out = relu(bias + [hbf | S] @ Wstack)   (K=640 MFMA GEMM, relu fused)
__global__ __launch_bounds__(256) void gemm_out(
        const unsigned short* __restrict__ hbf,
        const unsigned short* __restrict__ S,
        const unsigned short* __restrict__ wt2,
        const float* __restrict__ bias,
        float* __restrict__ out) {
    int wv = threadIdx.x >> 6;
    int lane = threadIdx.x & 63;
    int n16 = lane & 15;
    int quad = lane >> 4;
    int r0w = (blockIdx.x * 4 + wv) * 32;

    f32x4 acc[2][8];
#pragma unroll
    for (int rt = 0; rt < 2; ++rt)
#pragma unroll
        for (int ct = 0; ct < 8; ++ct)
            acc[rt][ct] = (f32x4)0.f;

#pragma unroll
    for (int ks = 0; ks < 20; ++ks) {
        int k0 = ks * 32 + quad * 8;
        bf16x8 afrag[2];
#pragma unroll
        for (int rt = 0; rt < 2; ++rt) {
            int r = r0w + rt * 16 + n16;
            bf16x8 af = (bf16x8)0;
            if (r < N_NODES) {
                const unsigned short* ap = (k0 < 128)
                    ? (hbf + (size_t)r * 128 + k0)
                    : (S + (size_t)r * 512 + (k0 - 128));
                af = *(const bf16x8*)ap;
            }
            afrag[rt] = af;
        }
#pragma unroll
        for (int ct = 0; ct < 8; ++ct) {
            const unsigned short* bp = wt2 + (size_t)(ct * 16 + n16) * 640 + k0;
            bf16x8 bfrag = *(const bf16x8*)bp;
            acc[0][ct] = __builtin_amdgcn_mfma_f32_16x16x32_bf16(afrag[0], bfrag, acc[0][ct], 0, 0, 0);
            acc[1][ct] = __builtin_amdgcn_mfma_f32_16x16x32_bf16(afrag[1], bfrag, acc[1][ct], 0, 0, 0);
        }
    }

    // C/D layout: col = lane&15, row = quad*4 + reg
#pragma unroll
    for (int rt = 0; rt < 2; ++rt) {
        int rbase = r0w + rt * 16 + quad * 4;
#pragma unroll
        for (int ct = 0; ct < 8; ++ct) {
            int col = ct * 16 + n16;
            float bv = bias[col];
#pragma unroll
            for (int rg = 0; rg < 4; ++rg) {
                int r = rbase + rg;
                if (r < N_NODES)
                    out[(size_t)r * H_DIM + col] = fmaxf(acc[rt][ct][rg] + bv, 0.f);
            }
        }
    }
}

extern "C" void kernel_launch(void* const* d_in, const int* in_sizes, int n_in,
                              void* d_out, int out_size, void* d_ws, size_t ws_size,
                              hipStream_t stream) {
    const float* h       = (const float*)d_in[0];
    const float* norm    = (const float*)d_in[1];
    const float* basis_w = (const float*)d_in[2];
    const float* w_comp  = (const float*)d_in[3];
    const float* loop_w  = (const float*)d_in[4];
    const float* bias    = (const float*)d_in[5];
    const int*   src     = (const int*)d_in[6];
    const int*   dst     = (const int*)d_in[7];
    const int*   etype   = (const int*)d_in[8];
    float* out = (float*)d_out;

    // ws layout (bytes):
    char* base = (char*)d_ws;
    unsigned short* wt2        = (unsigned short*)(base + 0);          // 163,840
    unsigned short* hbf        = (unsigned short*)(base + 163840);     // 12,800,000
    unsigned short* S          = (unsigned short*)(base + 12963840);   // 51,200,000
    int*            cnt        = (int*)(base + 64163840);              // 200,000
    int*            offs       = (int*)(base + 64363840);              // 200,064
    int*            cursor     = (int*)(base + 64563904);              // 200,000
    int*            sorted_src = (int*)(base + 64763904);              // 3,200,000
    float4*         sorted_cf  = (float4*)(base + 67963904);           // 12,800,000
    int*            bsum       = (int*)(base + 80763904);              // 784
    int*            bpre       = (int*)(base + 80764688);              // 784
    // total ~80.8 MB

    transpose_w2<<<5, 256, 0, stream>>>(basis_w, loop_w, wt2);
    cast_h<<<3125, 256, 0, stream>>>(h, hbf);
    zero_cnt<<<196, 256, 0, stream>>>(cnt);
    hist_kernel<<<3125, 256, 0, stream>>>(dst, cnt);
    scan_local<<<196, 256, 0, stream>>>(cnt, offs, bsum);
    scan_bsum<<<1, 256, 0, stream>>>(bsum, bpre, offs);
    scan_add<<<196, 256, 0, stream>>>(offs, bpre, cursor);
    scatter_kernel<<<3125, 256, 0, stream>>>(src, dst, etype, norm, w_comp,
                                             cursor, sorted_src, sorted_cf);
    aggregate_kernel<<<12500, 256, 0, stream>>>(offs, sorted_src, sorted_cf, hbf, S);
    gemm_out<<<391, 256, 0, stream>>>(hbf, S, wt2, bias, out);
}